// Round 1
// baseline (584.233 us; speedup 1.0000x reference)
//
#include <hip/hip_runtime.h>
#include <hip/hip_bf16.h>

typedef __bf16 bf16;
typedef float f32x4 __attribute__((ext_vector_type(4)));
typedef bf16 bf16x8 __attribute__((ext_vector_type(8)));
typedef bf16 bf16x4 __attribute__((ext_vector_type(4)));

#define MFMA16(a, b, c) __builtin_amdgcn_mfma_f32_16x16x32_bf16((a), (b), (c), 0, 0, 0)

__device__ __forceinline__ bf16x4 cvt4(float4 v) {
    bf16x4 r; r[0] = (bf16)v.x; r[1] = (bf16)v.y; r[2] = (bf16)v.z; r[3] = (bf16)v.w; return r;
}
__device__ __forceinline__ bf16x4 cvt4(bf16x4 v) { return v; }

template <typename TA> struct VecT;
template <> struct VecT<float> { using t = float4; };
template <> struct VecT<bf16>  { using t = bf16x4; };

// ---------------------------------------------------------------------------
// GEMM mainloop: C[128,128] tile of A[M,K] @ B[N,K]^T, bf16 MFMA 16x16x32.
// A may be f32 (converted in staging) or bf16. B is always f32 weights.
// LDS padded to 40 cols (80 B row stride = 5*16B) -> conflict-free b128 reads.
// ---------------------------------------------------------------------------
template <typename TA>
__device__ __forceinline__ void gemm_main(const TA* __restrict__ A, const float* __restrict__ B,
                                          int K, int bm, int bn,
                                          bf16 (*As)[40], bf16 (*Bs)[40], f32x4 (&acc)[4][4]) {
    using VA = typename VecT<TA>::t;
    const int tid = threadIdx.x;
    const int lane = tid & 63;
    const int wave = tid >> 6;
    const int wr = wave >> 1, wc = wave & 1;
    const int lr = lane & 15, ls = lane >> 4;

    int rowA[4], colA[4];
#pragma unroll
    for (int i = 0; i < 4; ++i) { int q = i * 256 + tid; rowA[i] = q >> 3; colA[i] = (q & 7) * 4; }

    VA ra[4]; float4 rb[4];
#pragma unroll
    for (int i = 0; i < 4; ++i) ra[i] = *(const VA*)(A + (long)(bm + rowA[i]) * K + colA[i]);
#pragma unroll
    for (int i = 0; i < 4; ++i) rb[i] = *(const float4*)(B + (long)(bn + rowA[i]) * K + colA[i]);

    const f32x4 z = {0.f, 0.f, 0.f, 0.f};
#pragma unroll
    for (int mm = 0; mm < 4; ++mm)
#pragma unroll
        for (int nn = 0; nn < 4; ++nn) acc[mm][nn] = z;

    for (int k0 = 0; k0 < K; k0 += 32) {
        __syncthreads();
#pragma unroll
        for (int i = 0; i < 4; ++i) *(bf16x4*)(&As[rowA[i]][colA[i]]) = cvt4(ra[i]);
#pragma unroll
        for (int i = 0; i < 4; ++i) *(bf16x4*)(&Bs[rowA[i]][colA[i]]) = cvt4(rb[i]);
        __syncthreads();
        if (k0 + 32 < K) {
#pragma unroll
            for (int i = 0; i < 4; ++i) ra[i] = *(const VA*)(A + (long)(bm + rowA[i]) * K + k0 + 32 + colA[i]);
#pragma unroll
            for (int i = 0; i < 4; ++i) rb[i] = *(const float4*)(B + (long)(bn + rowA[i]) * K + k0 + 32 + colA[i]);
        }
        bf16x8 af[4], bfr[4];
#pragma unroll
        for (int mm = 0; mm < 4; ++mm) af[mm] = *(const bf16x8*)(&As[wr * 64 + mm * 16 + lr][ls * 8]);
#pragma unroll
        for (int nn = 0; nn < 4; ++nn) bfr[nn] = *(const bf16x8*)(&Bs[wc * 64 + nn * 16 + lr][ls * 8]);
#pragma unroll
        for (int mm = 0; mm < 4; ++mm)
#pragma unroll
            for (int nn = 0; nn < 4; ++nn) acc[mm][nn] = MFMA16(af[mm], bfr[nn], acc[mm][nn]);
    }
}

// MODE: 0 = f32 out (ld N), 1 = bf16 out (ld N), 2 = bf16 transposed out (ld M)
template <typename TA, int MODE>
__global__ __launch_bounds__(256) void gemm_bt(const TA* __restrict__ A, const float* __restrict__ B,
                                               void* __restrict__ Cp, int M, int N, int K, float scale) {
    __shared__ __align__(16) bf16 As[128][40];
    __shared__ __align__(16) bf16 Bs[128][40];
    f32x4 acc[4][4];
    const int bm = blockIdx.y * 128, bn = blockIdx.x * 128;
    gemm_main<TA>(A, B, K, bm, bn, As, Bs, acc);

    const int lane = threadIdx.x & 63, wave = threadIdx.x >> 6;
    const int wr = wave >> 1, wc = wave & 1, lr = lane & 15, ls = lane >> 4;
#pragma unroll
    for (int mm = 0; mm < 4; ++mm)
#pragma unroll
        for (int nn = 0; nn < 4; ++nn)
#pragma unroll
            for (int r = 0; r < 4; ++r) {
                int mg = bm + wr * 64 + mm * 16 + ls * 4 + r;
                int ng = bn + wc * 64 + nn * 16 + lr;
                float v = acc[mm][nn][r] * scale;
                if (MODE == 0) ((float*)Cp)[(long)mg * N + ng] = v;
                else if (MODE == 1) ((bf16*)Cp)[(long)mg * N + ng] = (bf16)v;
                else ((bf16*)Cp)[(long)ng * M + mg] = (bf16)v;
            }
}

// Fused K+V projection: grid.x 0..7 -> K (normal bf16 out), 8..15 -> V (transposed out)
__global__ __launch_bounds__(256) void gemm_kv(const float* __restrict__ A, const float* __restrict__ Wk,
                                               const float* __restrict__ Wv, bf16* __restrict__ Kout,
                                               bf16* __restrict__ VtOut, int M, int K) {
    __shared__ __align__(16) bf16 As[128][40];
    __shared__ __align__(16) bf16 Bs[128][40];
    const bool isV = blockIdx.x >= 8;
    const float* B = isV ? Wv : Wk;
    const int bn = (blockIdx.x & 7) * 128;
    const int bm = blockIdx.y * 128;
    f32x4 acc[4][4];
    gemm_main<float>(A, B, K, bm, bn, As, Bs, acc);

    const int lane = threadIdx.x & 63, wave = threadIdx.x >> 6;
    const int wr = wave >> 1, wc = wave & 1, lr = lane & 15, ls = lane >> 4;
#pragma unroll
    for (int mm = 0; mm < 4; ++mm)
#pragma unroll
        for (int nn = 0; nn < 4; ++nn)
#pragma unroll
            for (int r = 0; r < 4; ++r) {
                int mg = bm + wr * 64 + mm * 16 + ls * 4 + r;
                int ng = bn + wc * 64 + nn * 16 + lr;
                float v = acc[mm][nn][r];
                if (!isV) Kout[(long)mg * 1024 + ng] = (bf16)v;
                else VtOut[(long)ng * M + mg] = (bf16)v;
            }
}

// ---------------------------------------------------------------------------
// Flash attention. Block = 128 q-rows of one head, 4 waves x 32 rows.
// K tile [64][128] and V tile [128][64] in XOR-swizzled LDS; P via wave-private
// swizzled LDS to convert MFMA C-layout -> A-layout.
// ---------------------------------------------------------------------------
__global__ __launch_bounds__(256) void flash_attn(const bf16* __restrict__ Q, const bf16* __restrict__ Kb,
                                                  const bf16* __restrict__ Vt, bf16* __restrict__ AO) {
    __shared__ __align__(16) bf16 Ks[64 * 128];
    __shared__ __align__(16) bf16 Vs[128 * 64];
    __shared__ __align__(16) bf16 Ps[4 * 32 * 64];
    const int tid = threadIdx.x, wave = tid >> 6, lane = tid & 63;
    const int lr = lane & 15, ls = lane >> 4;
    const int h = blockIdx.y, kvh = h >> 2;
    const int q0 = blockIdx.x * 128 + wave * 32;
    char* pbase = (char*)Ps + wave * 4096;

    bf16x8 aq[2][4];
#pragma unroll
    for (int rb = 0; rb < 2; ++rb)
#pragma unroll
        for (int f = 0; f < 4; ++f)
            aq[rb][f] = *(const bf16x8*)(Q + (long)(q0 + rb * 16 + lr) * 4096 + h * 128 + f * 32 + ls * 8);

    const f32x4 z = {0.f, 0.f, 0.f, 0.f};
    f32x4 acc[2][8];
    float mrun[2][4], lrun[2][4];
#pragma unroll
    for (int rb = 0; rb < 2; ++rb) {
#pragma unroll
        for (int d0 = 0; d0 < 8; ++d0) acc[rb][d0] = z;
#pragma unroll
        for (int r = 0; r < 4; ++r) { mrun[rb][r] = -1e30f; lrun[rb][r] = 0.f; }
    }

    for (int kt = 0; kt < 32; ++kt) {
        __syncthreads();
        // stage K tile (64 rows x 128 d), swizzle byte ^= (row&7)<<4
#pragma unroll
        for (int i = 0; i < 4; ++i) {
            int qq = i * 256 + tid; int row = qq >> 4, ch = qq & 15;
            bf16x8 v = *(const bf16x8*)(Kb + (long)(kt * 64 + row) * 1024 + kvh * 128 + ch * 8);
            int byte = row * 256 + ch * 16; byte ^= (row & 7) << 4;
            *(bf16x8*)((char*)Ks + byte) = v;
        }
        // stage V tile (128 d-rows x 64 s), swizzle byte ^= (d&7)<<4
#pragma unroll
        for (int i = 0; i < 4; ++i) {
            int qq = i * 256 + tid; int d = qq >> 3, ch = qq & 7;
            bf16x8 v = *(const bf16x8*)(Vt + (long)(kvh * 128 + d) * 2048 + kt * 64 + ch * 8);
            int byte = d * 128 + ch * 16; byte ^= (d & 7) << 4;
            *(bf16x8*)((char*)Vs + byte) = v;
        }
        __syncthreads();

        // scores: sc[rb][c] = Q[rb] @ K[c]^T  (16x16 frags, k-cols c*16..+15)
        f32x4 sc[2][4];
#pragma unroll
        for (int c = 0; c < 4; ++c) {
            bf16x8 bk[4];
#pragma unroll
            for (int f = 0; f < 4; ++f) {
                int row = c * 16 + lr;
                int byte = row * 256 + f * 64 + ls * 16; byte ^= (row & 7) << 4;
                bk[f] = *(const bf16x8*)((char*)Ks + byte);
            }
            sc[0][c] = z; sc[1][c] = z;
#pragma unroll
            for (int f = 0; f < 4; ++f) {
                sc[0][c] = MFMA16(aq[0][f], bk[f], sc[0][c]);
                sc[1][c] = MFMA16(aq[1][f], bk[f], sc[1][c]);
            }
        }

        // online softmax per row-block
#pragma unroll
        for (int rb = 0; rb < 2; ++rb) {
            float mn[4], corr[4], rs[4];
#pragma unroll
            for (int r = 0; r < 4; ++r) {
                float v = fmaxf(fmaxf(sc[rb][0][r], sc[rb][1][r]), fmaxf(sc[rb][2][r], sc[rb][3][r]));
#pragma unroll
                for (int off = 1; off < 16; off <<= 1) v = fmaxf(v, __shfl_xor(v, off, 64));
                mn[r] = fmaxf(mrun[rb][r], v);
                corr[r] = __expf(mrun[rb][r] - mn[r]);
                mrun[rb][r] = mn[r];
                rs[r] = 0.f;
            }
#pragma unroll
            for (int c = 0; c < 4; ++c)
#pragma unroll
                for (int r = 0; r < 4; ++r) {
                    float p = __expf(sc[rb][c][r] - mn[r]);
                    rs[r] += p;
                    int row = rb * 16 + ls * 4 + r;
                    int byte = row * 128 + (c * 16 + lr) * 2; byte ^= (row & 7) << 4;
                    *(bf16*)(pbase + byte) = (bf16)p;
                }
#pragma unroll
            for (int r = 0; r < 4; ++r) {
                float v = rs[r];
#pragma unroll
                for (int off = 1; off < 16; off <<= 1) v += __shfl_xor(v, off, 64);
                lrun[rb][r] = lrun[rb][r] * corr[r] + v;
            }
#pragma unroll
            for (int d0 = 0; d0 < 8; ++d0) {
                acc[rb][d0][0] *= corr[0]; acc[rb][d0][1] *= corr[1];
                acc[rb][d0][2] *= corr[2]; acc[rb][d0][3] *= corr[3];
            }
        }

        // PV: acc[rb][d0] += P[rb] @ V
        bf16x8 pa[2][2];
#pragma unroll
        for (int rb = 0; rb < 2; ++rb)
#pragma unroll
            for (int kk = 0; kk < 2; ++kk) {
                int row = rb * 16 + lr;
                int byte = row * 128 + kk * 64 + ls * 16; byte ^= (row & 7) << 4;
                pa[rb][kk] = *(const bf16x8*)(pbase + byte);
            }
#pragma unroll
        for (int d0 = 0; d0 < 8; ++d0) {
            int d = d0 * 16 + lr;
            int b0 = (d * 128 + ls * 16) ^ ((d & 7) << 4);
            int b1 = (d * 128 + 64 + ls * 16) ^ ((d & 7) << 4);
            bf16x8 bv0 = *(const bf16x8*)((char*)Vs + b0);
            bf16x8 bv1 = *(const bf16x8*)((char*)Vs + b1);
#pragma unroll
            for (int rb = 0; rb < 2; ++rb) {
                acc[rb][d0] = MFMA16(pa[rb][0], bv0, acc[rb][d0]);
                acc[rb][d0] = MFMA16(pa[rb][1], bv1, acc[rb][d0]);
            }
        }
    }

    // epilogue: AO[s, h*128+d] = acc / l
#pragma unroll
    for (int rb = 0; rb < 2; ++rb)
#pragma unroll
        for (int d0 = 0; d0 < 8; ++d0)
#pragma unroll
            for (int r = 0; r < 4; ++r) {
                int srow = q0 + rb * 16 + ls * 4 + r;
                AO[(long)srow * 4096 + h * 128 + d0 * 16 + lr] = (bf16)(acc[rb][d0][r] / lrun[rb][r]);
            }
}

// caches: out[j][s][d] = K[s][(j>>2)*128+d] ; V from transposed Vt
__global__ __launch_bounds__(256) void cache_out(const bf16* __restrict__ Kb, const bf16* __restrict__ Vt,
                                                 float* __restrict__ out) {
    int idx = blockIdx.x * 256 + threadIdx.x;  // 0 .. 8*2048*128-1
    int d = idx & 127;
    int s = (idx >> 7) & 2047;
    int j = idx >> 18;
    int hk = j >> 2;
    out[idx] = (float)Kb[(long)s * 1024 + hk * 128 + d];
    out[2097152 + idx] = (float)Vt[(long)(hk * 128 + d) * 2048 + s];
}

extern "C" void kernel_launch(void* const* d_in, const int* in_sizes, int n_in,
                              void* d_out, int out_size, void* d_ws, size_t ws_size,
                              hipStream_t stream) {
    const float* x  = (const float*)d_in[0];
    const float* Wq = (const float*)d_in[1];
    const float* Wk = (const float*)d_in[2];
    const float* Wv = (const float*)d_in[3];
    const float* Wo = (const float*)d_in[4];

    bf16* Qb = (bf16*)d_ws;                 // [2048,4096]
    bf16* Kb = Qb + (size_t)2048 * 4096;    // [2048,1024]
    bf16* Vt = Kb + (size_t)2048 * 1024;    // [1024,2048] transposed
    bf16* AO = Vt + (size_t)2048 * 1024;    // [2048,4096]
    float* out = (float*)d_out;
    float* cache = out + (size_t)2048 * 4096;

    const float qscale = 0.08838834764831845f;  // 1/sqrt(128)

    gemm_bt<float, 1><<<dim3(32, 16), 256, 0, stream>>>(x, Wq, (void*)Qb, 2048, 4096, 4096, qscale);
    gemm_kv<<<dim3(16, 16), 256, 0, stream>>>(x, Wk, Wv, Kb, Vt, 2048, 4096);
    flash_attn<<<dim3(16, 32), 256, 0, stream>>>(Qb, Kb, Vt, AO);
    gemm_bt<bf16, 0><<<dim3(32, 16), 256, 0, stream>>>(AO, Wo, d_out, 2048, 4096, 4096, 1.0f);
    cache_out<<<8192, 256, 0, stream>>>(Kb, Vt, cache);
}

// Round 2
// 569.192 us; speedup vs baseline: 1.0264x; 1.0264x over previous
//
#include <hip/hip_runtime.h>
#include <hip/hip_bf16.h>

typedef __bf16 bf16;
typedef float f32x4 __attribute__((ext_vector_type(4)));
typedef float f32x16 __attribute__((ext_vector_type(16)));
typedef bf16 bf16x8 __attribute__((ext_vector_type(8)));
typedef bf16 bf16x2 __attribute__((ext_vector_type(2)));
typedef unsigned u32x4 __attribute__((ext_vector_type(4)));

#define MFMA16(a,b,c) __builtin_amdgcn_mfma_f32_16x16x32_bf16((a),(b),(c),0,0,0)
#define MFMA32(a,b,c) __builtin_amdgcn_mfma_f32_32x32x16_bf16((a),(b),(c),0,0,0)

__device__ __forceinline__ void gload16(const void* g, void* l) {
    __builtin_amdgcn_global_load_lds((const __attribute__((address_space(1))) unsigned*)g,
                                     (__attribute__((address_space(3))) unsigned*)l, 16, 0, 0);
}

__device__ __forceinline__ unsigned pk(float lo, float hi) {
    bf16x2 t; t[0] = (bf16)lo; t[1] = (bf16)hi;
    return __builtin_bit_cast(unsigned, t);
}

// ---------------------------------------------------------------------------
// f32 -> bf16 convert (x only; weights stay f32 and are converted at GEMM
// fragment-read time from f32 staged directly into LDS by global_load_lds)
// ---------------------------------------------------------------------------
__global__ __launch_bounds__(256) void cvt_bf16(const float* __restrict__ in, bf16* __restrict__ out, int n8) {
    int i = blockIdx.x * 256 + threadIdx.x;
    if (i >= n8) return;
    const float4* p = (const float4*)in + (size_t)i * 2;
    float4 a = p[0], b = p[1];
    bf16x8 o;
    o[0]=(bf16)a.x; o[1]=(bf16)a.y; o[2]=(bf16)a.z; o[3]=(bf16)a.w;
    o[4]=(bf16)b.x; o[5]=(bf16)b.y; o[6]=(bf16)b.z; o[7]=(bf16)b.w;
    *((bf16x8*)out + i) = o;
}

// ---------------------------------------------------------------------------
// GEMM core: C[128,128] tile of A[M,K](bf16) @ B[N,K]^T(f32), m97-style:
// global_load_lds staging (A as bf16 8KB, B as raw f32 16KB), chunk-XOR
// pre-swizzled global sources, 2 barriers/K-step, 16x16x32 MFMA.
// ---------------------------------------------------------------------------
__device__ __forceinline__ void gemm_core(const bf16* __restrict__ A, const float* __restrict__ B,
                                          int K, int bm, int bn, bf16* As, float* Bs, f32x4 (&acc)[4][4]) {
    const int tid = threadIdx.x, lane = tid & 63, wv = tid >> 6;
    const int wr = wv >> 1, wc = wv & 1, lr = lane & 15, ls = lane >> 4;

#pragma unroll
    for (int mm=0;mm<4;++mm)
#pragma unroll
        for (int nn=0;nn<4;++nn)
#pragma unroll
            for (int r=0;r<4;++r) acc[mm][nn][r] = 0.f;

    for (int k0 = 0; k0 < K; k0 += 32) {
        __syncthreads();
        // stage A: bf16 [128][32] linear, source chunk-swizzled cg = cl ^ (row&3)
#pragma unroll
        for (int i=0;i<2;++i) {
            int off = i*4096 + wv*1024 + lane*16;
            int row = off >> 6;
            int cg = (lane & 3) ^ (row & 3);
            gload16(A + (size_t)(bm+row)*K + k0 + cg*8, (char*)As + i*4096 + wv*1024);
        }
        // stage B: f32 [128][32] linear, source chunk-swizzled cg = cl ^ (row&7)
#pragma unroll
        for (int i=0;i<4;++i) {
            int off = i*4096 + wv*1024 + lane*16;
            int row = off >> 7;
            int cg = (lane & 7) ^ (row & 7);
            gload16(B + (size_t)(bn+row)*K + k0 + cg*4, (char*)Bs + i*4096 + wv*1024);
        }
        __syncthreads();

        bf16x8 af[4], bfr[4];
#pragma unroll
        for (int mm=0;mm<4;++mm) {
            int row = wr*64 + mm*16 + lr;
            af[mm] = *(const bf16x8*)((char*)As + row*64 + ((ls ^ (row&3))<<4));
        }
#pragma unroll
        for (int nn=0;nn<4;++nn) {
            int row = wc*64 + nn*16 + lr;
            float4 b0 = *(const float4*)((char*)Bs + row*128 + (((ls*2  ) ^ (row&7))<<4));
            float4 b1 = *(const float4*)((char*)Bs + row*128 + (((ls*2+1) ^ (row&7))<<4));
            bf16x8 t;
            t[0]=(bf16)b0.x; t[1]=(bf16)b0.y; t[2]=(bf16)b0.z; t[3]=(bf16)b0.w;
            t[4]=(bf16)b1.x; t[5]=(bf16)b1.y; t[6]=(bf16)b1.z; t[7]=(bf16)b1.w;
            bfr[nn] = t;
        }
#pragma unroll
        for (int mm=0;mm<4;++mm)
#pragma unroll
            for (int nn=0;nn<4;++nn) acc[mm][nn] = MFMA16(af[mm], bfr[nn], acc[mm][nn]);
    }
}

// MODE: 0 = f32 out (ld N), 1 = bf16 out (ld N)
template <int MODE>
__global__ __launch_bounds__(256) void gemm_bt(const bf16* __restrict__ A, const float* __restrict__ B,
                                               void* __restrict__ Cp, int M, int N, int K, float scale) {
    __shared__ __align__(16) bf16  As[128*32];
    __shared__ __align__(16) float Bs[128*32];
    f32x4 acc[4][4];
    const int bm = blockIdx.y * 128, bn = blockIdx.x * 128;
    gemm_core(A, B, K, bm, bn, As, Bs, acc);

    const int lane = threadIdx.x & 63, wv = threadIdx.x >> 6;
    const int wr = wv >> 1, wc = wv & 1, lr = lane & 15, ls = lane >> 4;
#pragma unroll
    for (int mm=0;mm<4;++mm)
#pragma unroll
        for (int nn=0;nn<4;++nn)
#pragma unroll
            for (int r=0;r<4;++r) {
                int mg = bm + wr*64 + mm*16 + ls*4 + r;
                int ng = bn + wc*64 + nn*16 + lr;
                float v = acc[mm][nn][r] * scale;
                if (MODE == 0) ((float*)Cp)[(size_t)mg * N + ng] = v;
                else ((bf16*)Cp)[(size_t)mg * N + ng] = (bf16)v;
            }
}

// Fused K+V projection: grid.x 0..7 -> K (bf16, ld 1024), 8..15 -> V (bf16 transposed, ld M)
__global__ __launch_bounds__(256) void gemm_kv(const bf16* __restrict__ A, const float* __restrict__ Wk,
                                               const float* __restrict__ Wv, bf16* __restrict__ Kout,
                                               bf16* __restrict__ VtOut, int M, int K) {
    __shared__ __align__(16) bf16  As[128*32];
    __shared__ __align__(16) float Bs[128*32];
    const bool isV = blockIdx.x >= 8;
    const float* B = isV ? Wv : Wk;
    const int bn = (blockIdx.x & 7) * 128;
    const int bm = blockIdx.y * 128;
    f32x4 acc[4][4];
    gemm_core(A, B, K, bm, bn, As, Bs, acc);

    const int lane = threadIdx.x & 63, wv = threadIdx.x >> 6;
    const int wr = wv >> 1, wc = wv & 1, lr = lane & 15, ls = lane >> 4;
#pragma unroll
    for (int mm=0;mm<4;++mm)
#pragma unroll
        for (int nn=0;nn<4;++nn)
#pragma unroll
            for (int r=0;r<4;++r) {
                int mg = bm + wr*64 + mm*16 + ls*4 + r;
                int ng = bn + wc*64 + nn*16 + lr;
                float v = acc[mm][nn][r];
                if (!isV) Kout[(size_t)mg * 1024 + ng] = (bf16)v;
                else VtOut[(size_t)ng * M + mg] = (bf16)v;
            }
}

// ---------------------------------------------------------------------------
// Flash attention, 8 waves x 32 q-rows (block = 256 q-rows of one head).
// Swapped QK^T (mfma(K,Q) -> lane owns full P-column for q=lane&31),
// in-register softmax, defer-max (THR=8), P->A-frag via pack + partner shfl,
// K/V double-buffered in LDS via global_load_lds w/ pre-swizzled source.
// ---------------------------------------------------------------------------
__device__ __forceinline__ void stage_kv(const bf16* __restrict__ Kb, const bf16* __restrict__ Vt,
                                         char* Ks, char* Vs, int kvh, int kt, int buf,
                                         int wv, int lane) {
#pragma unroll
    for (int i=0;i<2;++i) {                       // K tile [64 rows][128 d] bf16, 16KB
        int off = i*8192 + wv*1024 + lane*16;
        int row = off >> 8;
        int cg = (lane & 15) ^ (row & 7);
        gload16(Kb + (size_t)(kt*64+row)*1024 + kvh*128 + cg*8, Ks + buf*16384 + i*8192 + wv*1024);
    }
#pragma unroll
    for (int i=0;i<2;++i) {                       // V tile [128 d][64 s] bf16, 16KB
        int off = i*8192 + wv*1024 + lane*16;
        int d = off >> 7;
        int cg = (lane & 7) ^ (d & 7);
        gload16(Vt + (size_t)(kvh*128+d)*2048 + kt*64 + cg*8, Vs + buf*16384 + i*8192 + wv*1024);
    }
}

__global__ __launch_bounds__(512) void flash_attn(const bf16* __restrict__ Q, const bf16* __restrict__ Kb,
                                                  const bf16* __restrict__ Vt, bf16* __restrict__ AO) {
    __shared__ __align__(16) char Ks[2*16384];
    __shared__ __align__(16) char Vs[2*16384];
    const int tid = threadIdx.x, lane = tid & 63, wq = tid >> 6;
    const int l31 = lane & 31, hi = lane >> 5;
    const int h = blockIdx.y, kvh = h >> 2;
    const int q0w = blockIdx.x * 256 + wq * 32;

    // Q as B-fragments: qf[f] = Q[q0w + l31][f*16 + hi*8 + j]
    bf16x8 qf[8];
#pragma unroll
    for (int f=0; f<8; ++f)
        qf[f] = *(const bf16x8*)(Q + (size_t)(q0w + l31)*4096 + h*128 + f*16 + hi*8);

    f32x16 acc[4];
#pragma unroll
    for (int db=0;db<4;++db)
#pragma unroll
        for (int r=0;r<16;++r) acc[db][r] = 0.f;
    float mrun = -1e30f, lrun = 0.f;

    stage_kv(Kb, Vt, Ks, Vs, kvh, 0, 0, wq, lane);
    __syncthreads();

    for (int t = 0; t < 32; ++t) {
        const int cur = t & 1;
        if (t + 1 < 32) stage_kv(Kb, Vt, Ks, Vs, kvh, t+1, cur^1, wq, lane);

        // QK^T: sc[kc] = S^T[k = kc*32 + crow(r,hi)][q = q0w + l31]
        const char* KsB = Ks + cur*16384;
        f32x16 sc[2];
#pragma unroll
        for (int kc=0;kc<2;++kc)
#pragma unroll
            for (int r=0;r<16;++r) sc[kc][r] = 0.f;
#pragma unroll
        for (int f=0; f<8; ++f) {
            int r0 = l31, r1 = 32 + l31;
            bf16x8 k0 = *(const bf16x8*)(KsB + r0*256 + (((f*2+hi) ^ (r0&7))<<4));
            bf16x8 k1 = *(const bf16x8*)(KsB + r1*256 + (((f*2+hi) ^ (r1&7))<<4));
            sc[0] = MFMA32(k0, qf[f], sc[0]);
            sc[1] = MFMA32(k1, qf[f], sc[1]);
        }

        // online softmax (per-lane row q = l31; partner lane l^32 holds complementary k)
        float tmax = sc[0][0];
#pragma unroll
        for (int r=1;r<16;++r) tmax = fmaxf(tmax, sc[0][r]);
#pragma unroll
        for (int r=0;r<16;++r) tmax = fmaxf(tmax, sc[1][r]);
        tmax = fmaxf(tmax, __shfl_xor(tmax, 32, 64));
        if (!__all(tmax <= mrun + 8.f)) {
            float mnew = fmaxf(mrun, tmax);
            float corr = __expf(mrun - mnew);
            mrun = mnew;
            lrun *= corr;
#pragma unroll
            for (int r=0;r<16;++r) {
                float cr = __shfl(corr, (r&3) + 8*(r>>2) + 4*hi, 64);
#pragma unroll
                for (int db=0;db<4;++db) acc[db][r] *= cr;
            }
        }
        float rs = 0.f;
#pragma unroll
        for (int kc=0;kc<2;++kc)
#pragma unroll
            for (int r=0;r<16;++r) { float e = __expf(sc[kc][r] - mrun); sc[kc][r] = e; rs += e; }
        rs += __shfl_xor(rs, 32, 64);
        lrun += rs;

        // P -> A-fragments: pa[kb] lane holds P[k = kb*16 + hi*8 + j][q = l31]
        bf16x8 pa[4];
#pragma unroll
        for (int kb=0;kb<4;++kb) {
            const int kc = kb>>1, r0 = (kb&1)*8;
            unsigned a0 = pk(sc[kc][r0+0], sc[kc][r0+1]);
            unsigned a1 = pk(sc[kc][r0+2], sc[kc][r0+3]);
            unsigned b0 = pk(sc[kc][r0+4], sc[kc][r0+5]);
            unsigned b1 = pk(sc[kc][r0+6], sc[kc][r0+7]);
            unsigned sa0 = (unsigned)__shfl_xor((int)a0, 32, 64);
            unsigned sa1 = (unsigned)__shfl_xor((int)a1, 32, 64);
            unsigned sb0 = (unsigned)__shfl_xor((int)b0, 32, 64);
            unsigned sb1 = (unsigned)__shfl_xor((int)b1, 32, 64);
            u32x4 w;
            w[0] = hi ? sb0 : a0;
            w[1] = hi ? sb1 : a1;
            w[2] = hi ? b0 : sa0;
            w[3] = hi ? b1 : sa1;
            pa[kb] = __builtin_bit_cast(bf16x8, w);
        }

        // PV: acc[db] += P @ V  (B-frag = Vt tile rows d, k contiguous)
        const char* VsB = Vs + cur*16384;
#pragma unroll
        for (int db=0;db<4;++db) {
            const int d = db*32 + l31;
#pragma unroll
            for (int kb=0;kb<4;++kb) {
                bf16x8 vf = *(const bf16x8*)(VsB + d*128 + (((kb*2+hi) ^ (d&7))<<4));
                acc[db] = MFMA32(pa[kb], vf, acc[db]);
            }
        }
        __syncthreads();
    }

    // epilogue: AO[q][h*128 + d] = acc / l   (acc row q = crow(r,hi), col d = db*32 + l31)
    float linv = 1.0f / lrun;
#pragma unroll
    for (int r=0;r<16;++r) {
        int crw = (r&3) + 8*(r>>2) + 4*hi;
        float lv = __shfl(linv, crw, 64);
        size_t qrow = (size_t)q0w + crw;
#pragma unroll
        for (int db=0;db<4;++db)
            AO[qrow*4096 + h*128 + db*32 + l31] = (bf16)(acc[db][r] * lv);
    }
}

// caches: out[j][s][d] = K[s][(j>>2)*128+d] ; V from transposed Vt
__global__ __launch_bounds__(256) void cache_out(const bf16* __restrict__ Kb, const bf16* __restrict__ Vt,
                                                 float* __restrict__ out) {
    int idx = blockIdx.x * 256 + threadIdx.x;  // 0 .. 8*2048*128-1
    int d = idx & 127;
    int s = (idx >> 7) & 2047;
    int j = idx >> 18;
    int hk = j >> 2;
    out[idx] = (float)Kb[(size_t)s * 1024 + hk * 128 + d];
    out[2097152 + idx] = (float)Vt[(size_t)(hk * 128 + d) * 2048 + s];
}

extern "C" void kernel_launch(void* const* d_in, const int* in_sizes, int n_in,
                              void* d_out, int out_size, void* d_ws, size_t ws_size,
                              hipStream_t stream) {
    const float* x  = (const float*)d_in[0];
    const float* Wq = (const float*)d_in[1];
    const float* Wk = (const float*)d_in[2];
    const float* Wv = (const float*)d_in[3];
    const float* Wo = (const float*)d_in[4];

    bf16* xb = (bf16*)d_ws;                 // [2048,4096] bf16 x
    bf16* Qb = xb + (size_t)2048 * 4096;    // [2048,4096] Q (later aliased as AO)
    bf16* Kb = Qb + (size_t)2048 * 4096;    // [2048,1024]
    bf16* Vt = Kb + (size_t)2048 * 1024;    // [1024,2048] transposed V
    float* out = (float*)d_out;
    float* cache = out + (size_t)2048 * 4096;

    const float qscale = 0.08838834764831845f;  // 1/sqrt(128)

    cvt_bf16<<<4096, 256, 0, stream>>>(x, xb, 1048576);
    gemm_bt<1><<<dim3(32, 16), 256, 0, stream>>>(xb, Wq, (void*)Qb, 2048, 4096, 4096, qscale);
    gemm_kv<<<dim3(16, 16), 256, 0, stream>>>(xb, Wk, Wv, Kb, Vt, 2048, 4096);
    flash_attn<<<dim3(8, 32), 512, 0, stream>>>(Qb, Kb, Vt, Qb /* AO aliases Qb: block-unique regions */);
    gemm_bt<0><<<dim3(32, 16), 256, 0, stream>>>(Qb, Wo, d_out, 2048, 4096, 4096, 1.0f);
    cache_out<<<8192, 256, 0, stream>>>(Kb, Vt, cache);
}

// Round 3
// 371.328 us; speedup vs baseline: 1.5734x; 1.5329x over previous
//
#include <hip/hip_runtime.h>
#include <hip/hip_bf16.h>

typedef __bf16 bf16;
typedef float f32x4 __attribute__((ext_vector_type(4)));
typedef float f32x16 __attribute__((ext_vector_type(16)));
typedef bf16 bf16x8 __attribute__((ext_vector_type(8)));
typedef bf16 bf16x2 __attribute__((ext_vector_type(2)));
typedef unsigned u32x4 __attribute__((ext_vector_type(4)));

#define MFMA16(a,b,c) __builtin_amdgcn_mfma_f32_16x16x32_bf16((a),(b),(c),0,0,0)
#define MFMA32(a,b,c) __builtin_amdgcn_mfma_f32_32x32x16_bf16((a),(b),(c),0,0,0)

__device__ __forceinline__ void gload16(const void* g, void* l) {
    __builtin_amdgcn_global_load_lds((const __attribute__((address_space(1))) unsigned*)g,
                                     (__attribute__((address_space(3))) unsigned*)l, 16, 0, 0);
}

__device__ __forceinline__ unsigned pk(float lo, float hi) {
    bf16x2 t; t[0] = (bf16)lo; t[1] = (bf16)hi;
    return __builtin_bit_cast(unsigned, t);
}

// ---------------------------------------------------------------------------
// f32 -> bf16 converters (x + all weights, once; GEMMs then run pure bf16)
// ---------------------------------------------------------------------------
__device__ __forceinline__ void cvt8(const float* __restrict__ in, bf16* __restrict__ out, int i) {
    const float4* p = (const float4*)in + (size_t)i * 2;
    float4 a = p[0], b = p[1];
    bf16x8 o;
    o[0]=(bf16)a.x; o[1]=(bf16)a.y; o[2]=(bf16)a.z; o[3]=(bf16)a.w;
    o[4]=(bf16)b.x; o[5]=(bf16)b.y; o[6]=(bf16)b.z; o[7]=(bf16)b.w;
    *((bf16x8*)out + i) = o;
}

__global__ __launch_bounds__(256) void cvt_all(const float* __restrict__ x, const float* __restrict__ wq,
                                               const float* __restrict__ wk, const float* __restrict__ wv,
                                               bf16* __restrict__ xb, bf16* __restrict__ wqb,
                                               bf16* __restrict__ wkb, bf16* __restrict__ wvb) {
    int i = blockIdx.x * 256 + threadIdx.x;
    const float* src; bf16* dst; int n8;
    switch (blockIdx.y) {
        case 0: src = x;  dst = xb;  n8 = 1048576; break;
        case 1: src = wq; dst = wqb; n8 = 2097152; break;
        case 2: src = wk; dst = wkb; n8 = 524288;  break;
        default: src = wv; dst = wvb; n8 = 524288; break;
    }
    if (i < n8) cvt8(src, dst, i);
}

__global__ __launch_bounds__(256) void cvt_one(const float* __restrict__ in, bf16* __restrict__ out, int n8) {
    int i = blockIdx.x * 256 + threadIdx.x;
    if (i < n8) cvt8(in, out, i);
}

// ---------------------------------------------------------------------------
// GEMM core: C[128,128] tile of A[M,K](bf16) @ B[N,K]^T(bf16), m97-style:
// global_load_lds width-16 staging, BK=64 (128B LDS rows -> 8-chunk XOR
// swizzle, conflict-free b128 fragment reads), 2 barriers per K-step.
// ---------------------------------------------------------------------------
__device__ __forceinline__ void gemm_core(const bf16* __restrict__ A, const bf16* __restrict__ B,
                                          int K, int bm, int bn, bf16* As, bf16* Bs, f32x4 (&acc)[4][4]) {
    const int tid = threadIdx.x, lane = tid & 63, wv = tid >> 6;
    const int wr = wv >> 1, wc = wv & 1, lr = lane & 15, ls = lane >> 4;

#pragma unroll
    for (int mm=0;mm<4;++mm)
#pragma unroll
        for (int nn=0;nn<4;++nn)
#pragma unroll
            for (int r=0;r<4;++r) acc[mm][nn][r] = 0.f;

    for (int k0 = 0; k0 < K; k0 += 64) {
        __syncthreads();
        // stage A,B: bf16 [128][64] linear LDS; source chunk-swizzled cg = (lane&7)^(row&7)
#pragma unroll
        for (int i=0;i<4;++i) {
            int off = i*4096 + wv*1024 + lane*16;
            int row = off >> 7;
            int cg = (lane & 7) ^ (row & 7);
            gload16(A + (size_t)(bm+row)*K + k0 + cg*8, (char*)As + i*4096 + wv*1024);
        }
#pragma unroll
        for (int i=0;i<4;++i) {
            int off = i*4096 + wv*1024 + lane*16;
            int row = off >> 7;
            int cg = (lane & 7) ^ (row & 7);
            gload16(B + (size_t)(bn+row)*K + k0 + cg*8, (char*)Bs + i*4096 + wv*1024);
        }
        __syncthreads();

#pragma unroll
        for (int ks=0; ks<2; ++ks) {
            bf16x8 af[4], bfr[4];
#pragma unroll
            for (int mm=0;mm<4;++mm) {
                int row = wr*64 + mm*16 + lr;
                af[mm] = *(const bf16x8*)((char*)As + row*128 + (((ks*4+ls) ^ (row&7))<<4));
            }
#pragma unroll
            for (int nn=0;nn<4;++nn) {
                int row = wc*64 + nn*16 + lr;
                bfr[nn] = *(const bf16x8*)((char*)Bs + row*128 + (((ks*4+ls) ^ (row&7))<<4));
            }
#pragma unroll
            for (int mm=0;mm<4;++mm)
#pragma unroll
                for (int nn=0;nn<4;++nn) acc[mm][nn] = MFMA16(af[mm], bfr[nn], acc[mm][nn]);
        }
    }
}

// MODE: 0 = f32 out (ld N), 1 = bf16 out (ld N)
template <int MODE>
__global__ __launch_bounds__(256) void gemm_bt(const bf16* __restrict__ A, const bf16* __restrict__ B,
                                               void* __restrict__ Cp, int M, int N, int K, float scale) {
    __shared__ __align__(16) bf16 As[128*64];
    __shared__ __align__(16) bf16 Bs[128*64];
    f32x4 acc[4][4];
    const int bm = blockIdx.y * 128, bn = blockIdx.x * 128;
    gemm_core(A, B, K, bm, bn, As, Bs, acc);

    const int lane = threadIdx.x & 63, wv = threadIdx.x >> 6;
    const int wr = wv >> 1, wc = wv & 1, lr = lane & 15, ls = lane >> 4;
#pragma unroll
    for (int mm=0;mm<4;++mm)
#pragma unroll
        for (int nn=0;nn<4;++nn)
#pragma unroll
            for (int r=0;r<4;++r) {
                int mg = bm + wr*64 + mm*16 + ls*4 + r;
                int ng = bn + wc*64 + nn*16 + lr;
                float v = acc[mm][nn][r] * scale;
                if (MODE == 0) ((float*)Cp)[(size_t)mg * N + ng] = v;
                else ((bf16*)Cp)[(size_t)mg * N + ng] = (bf16)v;
            }
}

// Fused K+V projection + f32 cache emission.
// grid.x 0..7 -> K (bf16, ld 1024), 8..15 -> V (bf16 transposed, ld M).
// cache[j][s][d] = {K,V}[s][(j>>2)*128+d]: cols ng<256 (kv-heads 0,1) write 4 copies.
__global__ __launch_bounds__(256) void gemm_kv(const bf16* __restrict__ A, const bf16* __restrict__ Wk,
                                               const bf16* __restrict__ Wv, bf16* __restrict__ Kout,
                                               bf16* __restrict__ VtOut, float* __restrict__ cacheK,
                                               float* __restrict__ cacheV, int M, int K) {
    __shared__ __align__(16) bf16 As[128*64];
    __shared__ __align__(16) bf16 Bs[128*64];
    const bool isV = blockIdx.x >= 8;
    const bf16* B = isV ? Wv : Wk;
    const int bn = (blockIdx.x & 7) * 128;
    const int bm = blockIdx.y * 128;
    f32x4 acc[4][4];
    gemm_core(A, B, K, bm, bn, As, Bs, acc);

    float* cache = isV ? cacheV : cacheK;
    const int lane = threadIdx.x & 63, wv = threadIdx.x >> 6;
    const int wr = wv >> 1, wc = wv & 1, lr = lane & 15, ls = lane >> 4;
#pragma unroll
    for (int mm=0;mm<4;++mm)
#pragma unroll
        for (int nn=0;nn<4;++nn)
#pragma unroll
            for (int r=0;r<4;++r) {
                int mg = bm + wr*64 + mm*16 + ls*4 + r;
                int ng = bn + wc*64 + nn*16 + lr;
                float v = acc[mm][nn][r];
                if (!isV) Kout[(size_t)mg * 1024 + ng] = (bf16)v;
                else VtOut[(size_t)ng * M + mg] = (bf16)v;
                if (ng < 256) {
                    int hk = ng >> 7, d = ng & 127;
#pragma unroll
                    for (int c=0;c<4;++c)
                        cache[((size_t)(hk*4+c)*2048 + mg)*128 + d] = v;
                }
            }
}

// ---------------------------------------------------------------------------
// Flash attention, 8 waves x 32 q-rows (block = 256 q-rows of one head).
// Swapped QK^T (mfma(K,Q) -> lane owns full P-column for q=lane&31),
// in-register softmax, defer-max (THR=8), P->A-frag via pack + partner shfl,
// K/V double-buffered in LDS via global_load_lds w/ pre-swizzled source.
// ---------------------------------------------------------------------------
__device__ __forceinline__ void stage_kv(const bf16* __restrict__ Kb, const bf16* __restrict__ Vt,
                                         char* Ks, char* Vs, int kvh, int kt, int buf,
                                         int wv, int lane) {
#pragma unroll
    for (int i=0;i<2;++i) {                       // K tile [64 rows][128 d] bf16, 16KB
        int off = i*8192 + wv*1024 + lane*16;
        int row = off >> 8;
        int cg = (lane & 15) ^ (row & 7);
        gload16(Kb + (size_t)(kt*64+row)*1024 + kvh*128 + cg*8, Ks + buf*16384 + i*8192 + wv*1024);
    }
#pragma unroll
    for (int i=0;i<2;++i) {                       // V tile [128 d][64 s] bf16, 16KB
        int off = i*8192 + wv*1024 + lane*16;
        int d = off >> 7;
        int cg = (lane & 7) ^ (d & 7);
        gload16(Vt + (size_t)(kvh*128+d)*2048 + kt*64 + cg*8, Vs + buf*16384 + i*8192 + wv*1024);
    }
}

__global__ __launch_bounds__(512) void flash_attn(const bf16* __restrict__ Q, const bf16* __restrict__ Kb,
                                                  const bf16* __restrict__ Vt, bf16* __restrict__ AO) {
    __shared__ __align__(16) char Ks[2*16384];
    __shared__ __align__(16) char Vs[2*16384];
    const int tid = threadIdx.x, lane = tid & 63, wq = tid >> 6;
    const int l31 = lane & 31, hi = lane >> 5;
    const int h = blockIdx.y, kvh = h >> 2;
    const int q0w = blockIdx.x * 256 + wq * 32;

    // Q as B-fragments: qf[f] = Q[q0w + l31][f*16 + hi*8 + j]
    bf16x8 qf[8];
#pragma unroll
    for (int f=0; f<8; ++f)
        qf[f] = *(const bf16x8*)(Q + (size_t)(q0w + l31)*4096 + h*128 + f*16 + hi*8);

    f32x16 acc[4];
#pragma unroll
    for (int db=0;db<4;++db)
#pragma unroll
        for (int r=0;r<16;++r) acc[db][r] = 0.f;
    float mrun = -1e30f, lrun = 0.f;

    stage_kv(Kb, Vt, Ks, Vs, kvh, 0, 0, wq, lane);
    __syncthreads();

    for (int t = 0; t < 32; ++t) {
        const int cur = t & 1;
        if (t + 1 < 32) stage_kv(Kb, Vt, Ks, Vs, kvh, t+1, cur^1, wq, lane);

        // QK^T: sc[kc] = S^T[k = kc*32 + crow(r,hi)][q = q0w + l31]
        const char* KsB = Ks + cur*16384;
        f32x16 sc[2];
#pragma unroll
        for (int kc=0;kc<2;++kc)
#pragma unroll
            for (int r=0;r<16;++r) sc[kc][r] = 0.f;
#pragma unroll
        for (int f=0; f<8; ++f) {
            int r0 = l31, r1 = 32 + l31;
            bf16x8 k0 = *(const bf16x8*)(KsB + r0*256 + (((f*2+hi) ^ (r0&7))<<4));
            bf16x8 k1 = *(const bf16x8*)(KsB + r1*256 + (((f*2+hi) ^ (r1&7))<<4));
            sc[0] = MFMA32(k0, qf[f], sc[0]);
            sc[1] = MFMA32(k1, qf[f], sc[1]);
        }

        // online softmax (per-lane row q = l31; partner lane l^32 holds complementary k)
        float tmax = sc[0][0];
#pragma unroll
        for (int r=1;r<16;++r) tmax = fmaxf(tmax, sc[0][r]);
#pragma unroll
        for (int r=0;r<16;++r) tmax = fmaxf(tmax, sc[1][r]);
        tmax = fmaxf(tmax, __shfl_xor(tmax, 32, 64));
        if (!__all(tmax <= mrun + 8.f)) {
            float mnew = fmaxf(mrun, tmax);
            float corr = __expf(mrun - mnew);
            mrun = mnew;
            lrun *= corr;
#pragma unroll
            for (int r=0;r<16;++r) {
                float cr = __shfl(corr, (r&3) + 8*(r>>2) + 4*hi, 64);
#pragma unroll
                for (int db=0;db<4;++db) acc[db][r] *= cr;
            }
        }
        float rs = 0.f;
#pragma unroll
        for (int kc=0;kc<2;++kc)
#pragma unroll
            for (int r=0;r<16;++r) { float e = __expf(sc[kc][r] - mrun); sc[kc][r] = e; rs += e; }
        rs += __shfl_xor(rs, 32, 64);
        lrun += rs;

        // P -> A-fragments: pa[kb] lane holds P[k = kb*16 + hi*8 + j][q = l31]
        bf16x8 pa[4];
#pragma unroll
        for (int kb=0;kb<4;++kb) {
            const int kc = kb>>1, r0 = (kb&1)*8;
            unsigned a0 = pk(sc[kc][r0+0], sc[kc][r0+1]);
            unsigned a1 = pk(sc[kc][r0+2], sc[kc][r0+3]);
            unsigned b0 = pk(sc[kc][r0+4], sc[kc][r0+5]);
            unsigned b1 = pk(sc[kc][r0+6], sc[kc][r0+7]);
            unsigned sa0 = (unsigned)__shfl_xor((int)a0, 32, 64);
            unsigned sa1 = (unsigned)__shfl_xor((int)a1, 32, 64);
            unsigned sb0 = (unsigned)__shfl_xor((int)b0, 32, 64);
            unsigned sb1 = (unsigned)__shfl_xor((int)b1, 32, 64);
            u32x4 w;
            w[0] = hi ? sb0 : a0;
            w[1] = hi ? sb1 : a1;
            w[2] = hi ? b0 : sa0;
            w[3] = hi ? b1 : sa1;
            pa[kb] = __builtin_bit_cast(bf16x8, w);
        }

        // PV: acc[db] += P @ V  (B-frag = Vt tile rows d, k contiguous)
        const char* VsB = Vs + cur*16384;
#pragma unroll
        for (int db=0;db<4;++db) {
            const int d = db*32 + l31;
#pragma unroll
            for (int kb=0;kb<4;++kb) {
                bf16x8 vf = *(const bf16x8*)(VsB + d*128 + (((kb*2+hi) ^ (d&7))<<4));
                acc[db] = MFMA32(pa[kb], vf, acc[db]);
            }
        }
        __syncthreads();
    }

    // epilogue: AO[q][h*128 + d] = acc / l   (acc row q = crow(r,hi), col d = db*32 + l31)
    float linv = 1.0f / lrun;
#pragma unroll
    for (int r=0;r<16;++r) {
        int crw = (r&3) + 8*(r>>2) + 4*hi;
        float lv = __shfl(linv, crw, 64);
        size_t qrow = (size_t)q0w + crw;
#pragma unroll
        for (int db=0;db<4;++db)
            AO[qrow*4096 + h*128 + db*32 + l31] = (bf16)(acc[db][r] * lv);
    }
}

extern "C" void kernel_launch(void* const* d_in, const int* in_sizes, int n_in,
                              void* d_out, int out_size, void* d_ws, size_t ws_size,
                              hipStream_t stream) {
    const float* x  = (const float*)d_in[0];
    const float* Wq = (const float*)d_in[1];
    const float* Wk = (const float*)d_in[2];
    const float* Wv = (const float*)d_in[3];
    const float* Wo = (const float*)d_in[4];

    bf16* xb  = (bf16*)d_ws;                   // [2048,4096]
    bf16* Qb  = xb  + (size_t)8388608;         // [2048,4096] Q; later aliased as AO
    bf16* Kb  = Qb  + (size_t)8388608;         // [2048,1024]
    bf16* Vt  = Kb  + (size_t)2097152;         // [1024,2048] transposed V
    bf16* Wqb = Vt  + (size_t)2097152;         // [4096,4096]; later aliased as Wo(bf16)
    bf16* Wkb = Wqb + (size_t)16777216;        // [1024,4096]
    bf16* Wvb = Wkb + (size_t)4194304;         // [1024,4096]
    // total ws: 46,137,344 bf16 = 92.3 MB

    float* out = (float*)d_out;
    float* cacheK = out + (size_t)8388608;
    float* cacheV = cacheK + (size_t)2097152;

    const float qscale = 0.08838834764831845f;  // 1/sqrt(128)

    cvt_all<<<dim3(8192, 4), 256, 0, stream>>>(x, Wq, Wk, Wv, xb, Wqb, Wkb, Wvb);
    gemm_bt<1><<<dim3(32, 16), 256, 0, stream>>>(xb, Wqb, (void*)Qb, 2048, 4096, 4096, qscale);
    cvt_one<<<8192, 256, 0, stream>>>(Wo, Wqb, 2097152);  // Wo(bf16) overwrites Wqb (no longer needed)
    gemm_kv<<<dim3(16, 16), 256, 0, stream>>>(xb, Wkb, Wvb, Kb, Vt, cacheK, cacheV, 2048, 4096);
    flash_attn<<<dim3(8, 32), 512, 0, stream>>>(Qb, Kb, Vt, Qb /* AO aliases Qb */);
    gemm_bt<0><<<dim3(32, 16), 256, 0, stream>>>(Qb, Wqb /* = Wo bf16 */, d_out, 2048, 4096, 4096, 1.0f);
}